// Round 1
// baseline (2267.612 us; speedup 1.0000x reference)
//
#include <hip/hip_runtime.h>
#include <hip/hip_bf16.h>
#include <math.h>

#define WAVE 64
#define NEG_SLOPE 0.2f

// ---------------------------------------------------------------------------
// Tiny kernel: filt[l][c][r] = softmax_r(gt_w[l][c][:]) ; L*C = 4 rows, R = 3
// ---------------------------------------------------------------------------
__global__ void mkfilt(const float* __restrict__ gt_w, float* __restrict__ filt,
                       int rows /*L*C*/) {
    int i = threadIdx.x;
    if (i < rows) {
        const float* g = gt_w + i * 3;
        float m = fmaxf(g[0], fmaxf(g[1], g[2]));
        float e0 = __expf(g[0] - m), e1 = __expf(g[1] - m), e2 = __expf(g[2] - m);
        float s = e0 + e1 + e2;
        filt[i * 3 + 0] = e0 / s;
        filt[i * 3 + 1] = e1 / s;
        filt[i * 3 + 2] = e2 / s;
    }
}

// ---------------------------------------------------------------------------
// CSR build: histogram -> scan -> scatter (packed src|rel)
// ---------------------------------------------------------------------------
__global__ void hist_kernel(const int* __restrict__ dst, int* __restrict__ counts, int m) {
    int i = blockIdx.x * blockDim.x + threadIdx.x;
    if (i < m) atomicAdd(&counts[dst[i]], 1);
}

__global__ __launch_bounds__(1024) void scan_kernel(const int* __restrict__ counts,
                                                    int* __restrict__ rowp,
                                                    int* __restrict__ cursor, int n) {
    __shared__ int ssum[1024];
    int t = threadIdx.x;
    int chunk = (n + 1023) / 1024;
    int b0 = t * chunk;
    int b1 = b0 + chunk; if (b1 > n) b1 = n;
    int s = 0;
    for (int i = b0; i < b1; ++i) s += counts[i];
    ssum[t] = s;
    __syncthreads();
    // Hillis-Steele inclusive scan
    for (int off = 1; off < 1024; off <<= 1) {
        int v = (t >= off) ? ssum[t - off] : 0;
        __syncthreads();
        ssum[t] += v;
        __syncthreads();
    }
    int pre = (t == 0) ? 0 : ssum[t - 1];
    for (int i = b0; i < b1; ++i) {
        rowp[i] = pre;
        cursor[i] = pre;
        pre += counts[i];
    }
    if (t == 1023) rowp[n] = pre;
}

__global__ void scatter_kernel(const int* __restrict__ src, const int* __restrict__ dst,
                               const int* __restrict__ rel, int* __restrict__ cursor,
                               unsigned* __restrict__ csr, int m) {
    int i = blockIdx.x * blockDim.x + threadIdx.x;
    if (i < m) {
        int d = dst[i];
        int pos = atomicAdd(&cursor[d], 1);
        csr[pos] = (unsigned)src[i] | ((unsigned)rel[i] << 20);
    }
}

// ---------------------------------------------------------------------------
// GEMM: C[n,64] = A[n,64] @ W[64,64]   (row-major, 64-row tiles)
// ---------------------------------------------------------------------------
__global__ __launch_bounds__(256) void gemm64(const float* __restrict__ A,
                                              const float* __restrict__ W,
                                              float* __restrict__ C, int n) {
    __shared__ __align__(16) float sW[64 * 64];
    __shared__ __align__(16) float sA[64 * 68];   // stride 68 keeps 16B align + kills conflicts
    int t = threadIdx.x;
    int row0 = blockIdx.x * 64;
    for (int i = t * 4; i < 64 * 64; i += 1024)
        *(float4*)&sW[i] = *(const float4*)&W[i];
    int rows = n - row0; if (rows > 64) rows = 64;
    for (int i = t * 4; i < 64 * 64; i += 1024) {
        int r = i >> 6, cc = i & 63;
        float4 v = {0.f, 0.f, 0.f, 0.f};
        if (r < rows) v = *(const float4*)&A[(size_t)(row0 + r) * 64 + cc];
        *(float4*)&sA[r * 68 + cc] = v;
    }
    __syncthreads();
    int tr = (t >> 4) << 2;
    int tc = (t & 15) << 2;
    float acc[4][4] = {};
#pragma unroll
    for (int k = 0; k < 64; ++k) {
        float a0 = sA[(tr + 0) * 68 + k];
        float a1 = sA[(tr + 1) * 68 + k];
        float a2 = sA[(tr + 2) * 68 + k];
        float a3 = sA[(tr + 3) * 68 + k];
        float b0 = sW[k * 64 + tc + 0];
        float b1 = sW[k * 64 + tc + 1];
        float b2v = sW[k * 64 + tc + 2];
        float b3 = sW[k * 64 + tc + 3];
        acc[0][0] += a0 * b0; acc[0][1] += a0 * b1; acc[0][2] += a0 * b2v; acc[0][3] += a0 * b3;
        acc[1][0] += a1 * b0; acc[1][1] += a1 * b1; acc[1][2] += a1 * b2v; acc[1][3] += a1 * b3;
        acc[2][0] += a2 * b0; acc[2][1] += a2 * b1; acc[2][2] += a2 * b2v; acc[2][3] += a2 * b3;
        acc[3][0] += a3 * b0; acc[3][1] += a3 * b1; acc[3][2] += a3 * b2v; acc[3][3] += a3 * b3;
    }
    for (int i2 = 0; i2 < 4; ++i2) {
        int r = tr + i2;
        if (row0 + r < n) {
            float4 v = {acc[i2][0], acc[i2][1], acc[i2][2], acc[i2][3]};
            *(float4*)&C[(size_t)(row0 + r) * 64 + tc] = v;
        }
    }
}

// ---------------------------------------------------------------------------
// el/er: per-node dots with attn_l / attn_r. One wave per node.
// ---------------------------------------------------------------------------
__global__ __launch_bounds__(256) void eler_kernel(const float* __restrict__ ft,
                                                   const float* __restrict__ attn_l,
                                                   const float* __restrict__ attn_r,
                                                   float* __restrict__ el,
                                                   float* __restrict__ er, int n) {
    int w = (blockIdx.x * blockDim.x + threadIdx.x) >> 6;
    int lane = threadIdx.x & 63;
    if (w >= n) return;
    float f = ft[(size_t)w * 64 + lane];
    float xl = f * attn_l[lane];
    float xr = f * attn_r[lane];
    for (int off = 32; off; off >>= 1) {
        xl += __shfl_xor(xl, off);
        xr += __shfl_xor(xr, off);
    }
    if (lane == 0) { el[w] = xl; er[w] = xr; }
}

// ---------------------------------------------------------------------------
// GAT pass 1: per dst node (one wave):
//   degw = sum filt[rel];  m = max leaky(el[src]+er[v]);  s = sum exp(logit-m)
//   ft1[v] = (sum filt[rel] * ft[src]) / max(degw,>0?degw:1)
// ---------------------------------------------------------------------------
__global__ __launch_bounds__(256) void agg1_kernel(const int* __restrict__ rowp,
                                                   const unsigned* __restrict__ csr,
                                                   const float* __restrict__ ft,
                                                   const float* __restrict__ el,
                                                   const float* __restrict__ er,
                                                   const float* __restrict__ filt, int fo,
                                                   float* __restrict__ ft1,
                                                   float* __restrict__ mbuf,
                                                   float* __restrict__ sbuf, int n) {
    int w = (blockIdx.x * blockDim.x + threadIdx.x) >> 6;
    int lane = threadIdx.x & 63;
    if (w >= n) return;
    int base = rowp[w], end = rowp[w + 1];
    float f0 = filt[fo], f1 = filt[fo + 1], f2 = filt[fo + 2];
    float erv = er[w];
    // phase 1: lane-parallel over edges -> degw (sum), m (max)
    float degw = 0.f, mmax = -INFINITY;
    for (int j = base + lane; j < end; j += 64) {
        unsigned pk = csr[j];
        int s = pk & 0xFFFFF;
        int r = pk >> 20;
        degw += (r == 0) ? f0 : ((r == 1) ? f1 : f2);
        float x = el[s] + erv;
        float lg = x > 0.f ? x : NEG_SLOPE * x;
        mmax = fmaxf(mmax, lg);
    }
    for (int off = 32; off; off >>= 1) {
        degw += __shfl_xor(degw, off);
        mmax = fmaxf(mmax, __shfl_xor(mmax, off));
    }
    // phase 2: serial over edges, feature-parallel (lane = dim)
    float acc = 0.f, ssum = 0.f;
    for (int j = base; j < end; ++j) {
        unsigned pk = csr[j];
        int s = pk & 0xFFFFF;
        int r = pk >> 20;
        float wgt = (r == 0) ? f0 : ((r == 1) ? f1 : f2);
        float x = el[s] + erv;
        float lg = x > 0.f ? x : NEG_SLOPE * x;
        ssum += __expf(lg - mmax);
        acc += wgt * ft[(size_t)s * 64 + lane];
    }
    float dsafe = degw > 0.f ? degw : 1.f;
    ft1[(size_t)w * 64 + lane] = acc / dsafe;
    if (lane == 0) { mbuf[w] = mmax; sbuf[w] = ssum; }
}

// ---------------------------------------------------------------------------
// GAT pass 2: ft2[v] = (sum exp(leaky(el[src]+er[v]) - m[v]) * ft1[src]) / s[v]
// ---------------------------------------------------------------------------
__global__ __launch_bounds__(256) void agg2_kernel(const int* __restrict__ rowp,
                                                   const unsigned* __restrict__ csr,
                                                   const float* __restrict__ ft1,
                                                   const float* __restrict__ el,
                                                   const float* __restrict__ er,
                                                   const float* __restrict__ mbuf,
                                                   const float* __restrict__ sbuf,
                                                   float* __restrict__ ft2, int n) {
    int w = (blockIdx.x * blockDim.x + threadIdx.x) >> 6;
    int lane = threadIdx.x & 63;
    if (w >= n) return;
    int base = rowp[w], end = rowp[w + 1];
    float mv = mbuf[w], sv = sbuf[w], erv = er[w];
    float inv = sv > 0.f ? 1.f / sv : 0.f;
    float acc = 0.f;
    for (int j = base; j < end; ++j) {
        unsigned pk = csr[j];
        int s = pk & 0xFFFFF;
        float x = el[s] + erv;
        float lg = x > 0.f ? x : NEG_SLOPE * x;
        float p = __expf(lg - mv);
        acc += p * ft1[(size_t)s * 64 + lane];
    }
    ft2[(size_t)w * 64 + lane] = acc * inv;
}

// ---------------------------------------------------------------------------
// Final: out[n,50] (+)= lin_w[c] * (Hc @ W2) (+ b2 when c==0)
// ---------------------------------------------------------------------------
__global__ __launch_bounds__(256) void gemm_out(const float* __restrict__ A,
                                                const float* __restrict__ W2,
                                                const float* __restrict__ b2,
                                                const float* __restrict__ lin_w,
                                                float* __restrict__ out, int n, int c) {
    __shared__ __align__(16) float sW[64 * 50];
    __shared__ __align__(16) float sA[64 * 68];
    int t = threadIdx.x;
    int row0 = blockIdx.x * 64;
    for (int i = t; i < 64 * 50; i += 256) sW[i] = W2[i];
    int rows = n - row0; if (rows > 64) rows = 64;
    for (int i = t * 4; i < 64 * 64; i += 1024) {
        int r = i >> 6, cc = i & 63;
        float4 v = {0.f, 0.f, 0.f, 0.f};
        if (r < rows) v = *(const float4*)&A[(size_t)(row0 + r) * 64 + cc];
        *(float4*)&sA[r * 68 + cc] = v;
    }
    float lw = lin_w[c];
    __syncthreads();
    for (int i = t; i < 64 * 50; i += 256) {
        int r = i / 50, col = i - r * 50;
        if (row0 + r >= n) continue;
        float acc = 0.f;
#pragma unroll
        for (int k = 0; k < 64; ++k) acc += sA[r * 68 + k] * sW[k * 50 + col];
        size_t o = (size_t)(row0 + r) * 50 + col;
        float base = (c == 0) ? b2[col] : out[o];
        out[o] = base + lw * acc;
    }
}

// ---------------------------------------------------------------------------
extern "C" void kernel_launch(void* const* d_in, const int* in_sizes, int n_in,
                              void* d_out, int out_size, void* d_ws, size_t ws_size,
                              hipStream_t stream) {
    const float* h      = (const float*)d_in[0];
    const float* params = (const float*)d_in[1];
    const float* gt_w   = (const float*)d_in[2];
    const float* fc_w   = (const float*)d_in[3];
    const float* attn_l = (const float*)d_in[4];
    const float* attn_r = (const float*)d_in[5];
    const float* lin_w  = (const float*)d_in[6];
    const float* W2     = (const float*)d_in[7];
    const float* b2     = (const float*)d_in[8];
    const int*   src    = (const int*)d_in[9];
    const int*   dst    = (const int*)d_in[10];
    const int*   rel    = (const int*)d_in[11];

    const int n = in_sizes[0] / 64;      // 100000 nodes
    const int m = in_sizes[9];           // 1.8M edges
    const int C = 2, L = 2;
    float* out = (float*)d_out;

    // workspace layout (256B aligned slices)
    char* base = (char*)d_ws;
    size_t off = 0;
    auto alloc = [&](size_t bytes) -> char* {
        char* p = base + off;
        off = (off + bytes + 255) & ~(size_t)255;
        return p;
    };
    float*    filt   = (float*)alloc(L * C * 3 * sizeof(float));
    int*      counts = (int*)alloc((size_t)n * 4);
    int*      cursor = (int*)alloc((size_t)n * 4);
    int*      rowp   = (int*)alloc((size_t)(n + 1) * 4);
    unsigned* csr    = (unsigned*)alloc((size_t)m * 4);
    float*    el     = (float*)alloc((size_t)n * 4);
    float*    er     = (float*)alloc((size_t)n * 4);
    float*    mbuf   = (float*)alloc((size_t)n * 4);
    float*    sbuf   = (float*)alloc((size_t)n * 4);
    float*    bufA   = (float*)alloc((size_t)n * 64 * 4);
    float*    bufB   = (float*)alloc((size_t)n * 64 * 4);
    float*    bufC   = (float*)alloc((size_t)n * 64 * 4);

    // ---- CSR build (once per call; shared by all layers/channels) ----
    hipMemsetAsync(counts, 0, (size_t)n * 4, stream);
    mkfilt<<<1, 64, 0, stream>>>(gt_w, filt, L * C);
    hist_kernel<<<(m + 255) / 256, 256, 0, stream>>>(dst, counts, m);
    scan_kernel<<<1, 1024, 0, stream>>>(counts, rowp, cursor, n);
    scatter_kernel<<<(m + 255) / 256, 256, 0, stream>>>(src, dst, rel, cursor, csr, m);

    const int gemmBlocks = (n + 63) / 64;
    const int waveBlocks = (n + 3) / 4;    // 1 wave per node, 4 waves per block

    for (int c = 0; c < C; ++c) {
        // Hc = h @ params[c]
        gemm64<<<gemmBlocks, 256, 0, stream>>>(h, params + (size_t)c * 64 * 64, bufA, n);
        for (int l = 0; l < L; ++l) {
            // ft = Hc @ fc_w
            gemm64<<<gemmBlocks, 256, 0, stream>>>(bufA, fc_w, bufB, n);
            // el, er
            eler_kernel<<<waveBlocks, 256, 0, stream>>>(bufB, attn_l, attn_r, el, er, n);
            // pass 1: ft1 + softmax stats
            int fo = (l * C + c) * 3;
            agg1_kernel<<<waveBlocks, 256, 0, stream>>>(rowp, csr, bufB, el, er, filt, fo,
                                                        bufC, mbuf, sbuf, n);
            // pass 2: ft2 -> becomes Hc for next layer
            agg2_kernel<<<waveBlocks, 256, 0, stream>>>(rowp, csr, bufC, el, er, mbuf, sbuf,
                                                        bufA, n);
        }
        // out (+)= lin_w[c] * (Hc @ W2) (+ b2 on first channel)
        gemm_out<<<gemmBlocks, 256, 0, stream>>>(bufA, W2, b2, lin_w, out, n, c);
    }
}

// Round 2
// 1972.514 us; speedup vs baseline: 1.1496x; 1.1496x over previous
//
#include <hip/hip_runtime.h>
#include <hip/hip_bf16.h>
#include <math.h>

#define NEG_SLOPE 0.2f

// ---------------------------------------------------------------------------
// filt[l][c][r] = softmax_r(gt_w[l][c][:]) ; L*C = 4 rows, R = 3
// ---------------------------------------------------------------------------
__global__ void mkfilt(const float* __restrict__ gt_w, float* __restrict__ filt,
                       int rows /*L*C*/) {
    int i = threadIdx.x;
    if (i < rows) {
        const float* g = gt_w + i * 3;
        float m = fmaxf(g[0], fmaxf(g[1], g[2]));
        float e0 = __expf(g[0] - m), e1 = __expf(g[1] - m), e2 = __expf(g[2] - m);
        float s = e0 + e1 + e2;
        filt[i * 3 + 0] = e0 / s;
        filt[i * 3 + 1] = e1 / s;
        filt[i * 3 + 2] = e2 / s;
    }
}

// ---------------------------------------------------------------------------
// CSR build: histogram -> 3-phase parallel scan -> scatter (packed src|rel)
// ---------------------------------------------------------------------------
__global__ void hist_kernel(const int* __restrict__ dst, int* __restrict__ counts, int m) {
    int i = blockIdx.x * blockDim.x + threadIdx.x;
    if (i < m) atomicAdd(&counts[dst[i]], 1);
}

// per-256-chunk sums (coalesced)
__global__ __launch_bounds__(256) void blocksum_kernel(const int* __restrict__ counts,
                                                       int* __restrict__ bsum, int n) {
    __shared__ int red[4];
    int i = blockIdx.x * 256 + threadIdx.x;
    int v = (i < n) ? counts[i] : 0;
    for (int off = 32; off; off >>= 1) v += __shfl_xor(v, off);
    if ((threadIdx.x & 63) == 0) red[threadIdx.x >> 6] = v;
    __syncthreads();
    if (threadIdx.x == 0) bsum[blockIdx.x] = red[0] + red[1] + red[2] + red[3];
}

// exclusive scan of nb (<512) block sums, in place
__global__ __launch_bounds__(512) void scanb_kernel(int* __restrict__ bsum, int nb) {
    __shared__ int s[512];
    int t = threadIdx.x;
    int v = (t < nb) ? bsum[t] : 0;
    s[t] = v;
    __syncthreads();
    for (int off = 1; off < 512; off <<= 1) {
        int u = (t >= off) ? s[t - off] : 0;
        __syncthreads();
        s[t] += u;
        __syncthreads();
    }
    if (t < nb) bsum[t] = s[t] - v;   // exclusive
}

// per-block LDS scan + add base -> rowp/cursor
__global__ __launch_bounds__(256) void fill_kernel(const int* __restrict__ counts,
                                                   const int* __restrict__ bsum,
                                                   int* __restrict__ rowp,
                                                   int* __restrict__ cursor, int n, int m) {
    __shared__ int s[256];
    int t = threadIdx.x;
    int i = blockIdx.x * 256 + t;
    int v = (i < n) ? counts[i] : 0;
    s[t] = v;
    __syncthreads();
    for (int off = 1; off < 256; off <<= 1) {
        int u = (t >= off) ? s[t - off] : 0;
        __syncthreads();
        s[t] += u;
        __syncthreads();
    }
    if (i < n) {
        int ex = bsum[blockIdx.x] + s[t] - v;
        rowp[i] = ex;
        cursor[i] = ex;
    }
    if (i == 0) rowp[n] = m;
}

__global__ void scatter_kernel(const int* __restrict__ src, const int* __restrict__ dst,
                               const int* __restrict__ rel, int* __restrict__ cursor,
                               unsigned* __restrict__ csr, int m) {
    int i = blockIdx.x * blockDim.x + threadIdx.x;
    if (i < m) {
        int d = dst[i];
        int pos = atomicAdd(&cursor[d], 1);
        csr[pos] = (unsigned)src[i] | ((unsigned)rel[i] << 20);
    }
}

// ---------------------------------------------------------------------------
// GEMM: C[n,64] = A[n,64] @ W[64,64]; optional fused el/er epilogue
// (el[v] = C[v,:]·attn_l, er[v] = C[v,:]·attn_r)
// ---------------------------------------------------------------------------
__global__ __launch_bounds__(256) void gemm64(const float* __restrict__ A,
                                              const float* __restrict__ W,
                                              float* __restrict__ C, int n,
                                              const float* __restrict__ attn_l,
                                              const float* __restrict__ attn_r,
                                              float* __restrict__ el,
                                              float* __restrict__ er) {
    __shared__ __align__(16) float sW[64 * 64];
    __shared__ __align__(16) float sA[64 * 68];
    __shared__ float sAl[64], sAr[64];
    int t = threadIdx.x;
    int row0 = blockIdx.x * 64;
    for (int i = t * 4; i < 64 * 64; i += 1024)
        *(float4*)&sW[i] = *(const float4*)&W[i];
    if (el && t < 64) { sAl[t] = attn_l[t]; sAr[t] = attn_r[t]; }
    int rows = n - row0; if (rows > 64) rows = 64;
    for (int i = t * 4; i < 64 * 64; i += 1024) {
        int r = i >> 6, cc = i & 63;
        float4 v = {0.f, 0.f, 0.f, 0.f};
        if (r < rows) v = *(const float4*)&A[(size_t)(row0 + r) * 64 + cc];
        *(float4*)&sA[r * 68 + cc] = v;
    }
    __syncthreads();
    int tr = (t >> 4) << 2;
    int tc = (t & 15) << 2;
    float acc[4][4] = {};
#pragma unroll
    for (int k = 0; k < 64; k += 4) {
        float4 a0 = *(const float4*)&sA[(tr + 0) * 68 + k];
        float4 a1 = *(const float4*)&sA[(tr + 1) * 68 + k];
        float4 a2 = *(const float4*)&sA[(tr + 2) * 68 + k];
        float4 a3 = *(const float4*)&sA[(tr + 3) * 68 + k];
#pragma unroll
        for (int kk = 0; kk < 4; ++kk) {
            float4 b = *(const float4*)&sW[(k + kk) * 64 + tc];
            float v0 = (&a0.x)[kk], v1 = (&a1.x)[kk], v2 = (&a2.x)[kk], v3 = (&a3.x)[kk];
            acc[0][0] += v0 * b.x; acc[0][1] += v0 * b.y; acc[0][2] += v0 * b.z; acc[0][3] += v0 * b.w;
            acc[1][0] += v1 * b.x; acc[1][1] += v1 * b.y; acc[1][2] += v1 * b.z; acc[1][3] += v1 * b.w;
            acc[2][0] += v2 * b.x; acc[2][1] += v2 * b.y; acc[2][2] += v2 * b.z; acc[2][3] += v2 * b.w;
            acc[3][0] += v3 * b.x; acc[3][1] += v3 * b.y; acc[3][2] += v3 * b.z; acc[3][3] += v3 * b.w;
        }
    }
    for (int i2 = 0; i2 < 4; ++i2) {
        int r = tr + i2;
        if (row0 + r < n) {
            float4 v = {acc[i2][0], acc[i2][1], acc[i2][2], acc[i2][3]};
            *(float4*)&C[(size_t)(row0 + r) * 64 + tc] = v;
        }
    }
    if (el) {
        // per-thread partial dot over its 4 cols, reduce across the 16 threads
        // (same rows) via shfl_xor within the 16-lane group
        float pl[4], pr[4];
#pragma unroll
        for (int i2 = 0; i2 < 4; ++i2) {
            float l = 0.f, r = 0.f;
#pragma unroll
            for (int j = 0; j < 4; ++j) {
                l += acc[i2][j] * sAl[tc + j];
                r += acc[i2][j] * sAr[tc + j];
            }
            pl[i2] = l; pr[i2] = r;
        }
#pragma unroll
        for (int off = 1; off < 16; off <<= 1) {
#pragma unroll
            for (int i2 = 0; i2 < 4; ++i2) {
                pl[i2] += __shfl_xor(pl[i2], off);
                pr[i2] += __shfl_xor(pr[i2], off);
            }
        }
        if ((t & 15) == 0) {
#pragma unroll
            for (int i2 = 0; i2 < 4; ++i2) {
                int r = row0 + tr + i2;
                if (r < n) { el[r] = pl[i2]; er[r] = pr[i2]; }
            }
        }
    }
}

// ---------------------------------------------------------------------------
// GAT pass 1, one wave per dst node:
//  lane-par: degw = sum filt[rel];  m = max leaky(el[src]+er[v])
//  lane-par: e_j = exp(lg_j - m) -> abuf[j] (coalesced), ssum = sum e_j
//  serial  : ft1[v] = (sum filt[rel_j] * ft[src_j]) / (degw>0?degw:1)
//  sbuf[v] = 1/ssum
// ---------------------------------------------------------------------------
__global__ __launch_bounds__(256) void agg1_kernel(const int* __restrict__ rowp,
                                                   const unsigned* __restrict__ csr,
                                                   const float* __restrict__ ft,
                                                   const float* __restrict__ el,
                                                   const float* __restrict__ er,
                                                   const float* __restrict__ filt, int fo,
                                                   float* __restrict__ ft1,
                                                   float* __restrict__ abuf,
                                                   float* __restrict__ sbuf, int n) {
    int w = (blockIdx.x * blockDim.x + threadIdx.x) >> 6;
    int lane = threadIdx.x & 63;
    if (w >= n) return;
    int base = rowp[w], end = rowp[w + 1];
    float f0 = filt[fo], f1 = filt[fo + 1], f2 = filt[fo + 2];
    float erv = er[w];
    // phase 1: degw (sum), m (max), lane-parallel over edges
    float degw = 0.f, mmax = -INFINITY;
    for (int j = base + lane; j < end; j += 64) {
        unsigned pk = csr[j];
        int s = pk & 0xFFFFF;
        int r = pk >> 20;
        degw += (r == 0) ? f0 : ((r == 1) ? f1 : f2);
        float x = el[s] + erv;
        float lg = x > 0.f ? x : NEG_SLOPE * x;
        mmax = fmaxf(mmax, lg);
    }
    for (int off = 32; off; off >>= 1) {
        degw += __shfl_xor(degw, off);
        mmax = fmaxf(mmax, __shfl_xor(mmax, off));
    }
    // phase 2: e_j -> abuf (coalesced within segment), ssum
    float ssum = 0.f;
    for (int j = base + lane; j < end; j += 64) {
        unsigned pk = csr[j];
        int s = pk & 0xFFFFF;
        float x = el[s] + erv;
        float lg = x > 0.f ? x : NEG_SLOPE * x;
        float e = __expf(lg - mmax);
        abuf[j] = e;
        ssum += e;
    }
    for (int off = 32; off; off >>= 1) ssum += __shfl_xor(ssum, off);
    // phase 3: serial over edges, feature-parallel (lane = dim)
    float acc = 0.f;
    for (int j = base; j < end; ++j) {
        unsigned pk = csr[j];
        int s = pk & 0xFFFFF;
        int r = pk >> 20;
        float wgt = (r == 0) ? f0 : ((r == 1) ? f1 : f2);
        acc += wgt * ft[(size_t)s * 64 + lane];
    }
    float dsafe = degw > 0.f ? degw : 1.f;
    ft1[(size_t)w * 64 + lane] = acc / dsafe;
    if (lane == 0) sbuf[w] = (ssum > 0.f) ? 1.f / ssum : 0.f;
}

// ---------------------------------------------------------------------------
// GAT pass 2: ft2[v] = (sum_j abuf[j] * ft1[src_j]) * sbuf[v]
// ---------------------------------------------------------------------------
__global__ __launch_bounds__(256) void agg2_kernel(const int* __restrict__ rowp,
                                                   const unsigned* __restrict__ csr,
                                                   const float* __restrict__ ft1,
                                                   const float* __restrict__ abuf,
                                                   const float* __restrict__ sbuf,
                                                   float* __restrict__ ft2, int n) {
    int w = (blockIdx.x * blockDim.x + threadIdx.x) >> 6;
    int lane = threadIdx.x & 63;
    if (w >= n) return;
    int base = rowp[w], end = rowp[w + 1];
    float inv = sbuf[w];
    float acc = 0.f;
    for (int j = base; j < end; ++j) {
        unsigned pk = csr[j];
        int s = pk & 0xFFFFF;
        acc += abuf[j] * ft1[(size_t)s * 64 + lane];
    }
    ft2[(size_t)w * 64 + lane] = acc * inv;
}

// ---------------------------------------------------------------------------
// Final: out[n,50] (+)= lin_w[c] * (Hc @ W2) (+ b2 when c==0)
// ---------------------------------------------------------------------------
__global__ __launch_bounds__(256) void gemm_out(const float* __restrict__ A,
                                                const float* __restrict__ W2,
                                                const float* __restrict__ b2,
                                                const float* __restrict__ lin_w,
                                                float* __restrict__ out, int n, int c) {
    __shared__ __align__(16) float sW[64 * 50];
    __shared__ __align__(16) float sA[64 * 68];
    int t = threadIdx.x;
    int row0 = blockIdx.x * 64;
    for (int i = t; i < 64 * 50; i += 256) sW[i] = W2[i];
    int rows = n - row0; if (rows > 64) rows = 64;
    for (int i = t * 4; i < 64 * 64; i += 1024) {
        int r = i >> 6, cc = i & 63;
        float4 v = {0.f, 0.f, 0.f, 0.f};
        if (r < rows) v = *(const float4*)&A[(size_t)(row0 + r) * 64 + cc];
        *(float4*)&sA[r * 68 + cc] = v;
    }
    float lw = lin_w[c];
    __syncthreads();
    for (int i = t; i < 64 * 50; i += 256) {
        int r = i / 50, col = i - r * 50;
        if (row0 + r >= n) continue;
        float acc = 0.f;
#pragma unroll
        for (int k = 0; k < 64; ++k) acc += sA[r * 68 + k] * sW[k * 50 + col];
        size_t o = (size_t)(row0 + r) * 50 + col;
        float base = (c == 0) ? b2[col] : out[o];
        out[o] = base + lw * acc;
    }
}

// ---------------------------------------------------------------------------
extern "C" void kernel_launch(void* const* d_in, const int* in_sizes, int n_in,
                              void* d_out, int out_size, void* d_ws, size_t ws_size,
                              hipStream_t stream) {
    const float* h      = (const float*)d_in[0];
    const float* params = (const float*)d_in[1];
    const float* gt_w   = (const float*)d_in[2];
    const float* fc_w   = (const float*)d_in[3];
    const float* attn_l = (const float*)d_in[4];
    const float* attn_r = (const float*)d_in[5];
    const float* lin_w  = (const float*)d_in[6];
    const float* W2     = (const float*)d_in[7];
    const float* b2     = (const float*)d_in[8];
    const int*   src    = (const int*)d_in[9];
    const int*   dst    = (const int*)d_in[10];
    const int*   rel    = (const int*)d_in[11];

    const int n = in_sizes[0] / 64;      // 100000 nodes
    const int m = in_sizes[9];           // 1.8M edges
    const int C = 2, L = 2;
    float* out = (float*)d_out;

    // workspace layout (256B aligned slices)
    char* base = (char*)d_ws;
    size_t off = 0;
    auto alloc = [&](size_t bytes) -> char* {
        char* p = base + off;
        off = (off + bytes + 255) & ~(size_t)255;
        return p;
    };
    const int nb = (n + 255) / 256;      // 391 chunks
    float*    filt   = (float*)alloc(L * C * 3 * sizeof(float));
    int*      counts = (int*)alloc((size_t)n * 4);
    int*      cursor = (int*)alloc((size_t)n * 4);
    int*      rowp   = (int*)alloc((size_t)(n + 1) * 4);
    int*      bsum   = (int*)alloc((size_t)nb * 4);
    unsigned* csr    = (unsigned*)alloc((size_t)m * 4);
    float*    el     = (float*)alloc((size_t)n * 4);
    float*    er     = (float*)alloc((size_t)n * 4);
    float*    sbuf   = (float*)alloc((size_t)n * 4);
    float*    abuf   = (float*)alloc((size_t)m * 4);
    float*    bufA   = (float*)alloc((size_t)n * 64 * 4);
    float*    bufB   = (float*)alloc((size_t)n * 64 * 4);
    float*    bufC   = (float*)alloc((size_t)n * 64 * 4);

    // ---- CSR build (shared by all layers/channels) ----
    hipMemsetAsync(counts, 0, (size_t)n * 4, stream);
    mkfilt<<<1, 64, 0, stream>>>(gt_w, filt, L * C);
    hist_kernel<<<(m + 255) / 256, 256, 0, stream>>>(dst, counts, m);
    blocksum_kernel<<<nb, 256, 0, stream>>>(counts, bsum, n);
    scanb_kernel<<<1, 512, 0, stream>>>(bsum, nb);
    fill_kernel<<<nb, 256, 0, stream>>>(counts, bsum, rowp, cursor, n, m);
    scatter_kernel<<<(m + 255) / 256, 256, 0, stream>>>(src, dst, rel, cursor, csr, m);

    const int gemmBlocks = (n + 63) / 64;
    const int waveBlocks = (n + 3) / 4;    // 1 wave per node, 4 waves per block

    for (int c = 0; c < C; ++c) {
        // Hc = h @ params[c]
        gemm64<<<gemmBlocks, 256, 0, stream>>>(h, params + (size_t)c * 64 * 64, bufA, n,
                                               nullptr, nullptr, nullptr, nullptr);
        for (int l = 0; l < L; ++l) {
            // ft = Hc @ fc_w, fused el/er
            gemm64<<<gemmBlocks, 256, 0, stream>>>(bufA, fc_w, bufB, n,
                                                   attn_l, attn_r, el, er);
            int fo = (l * C + c) * 3;
            agg1_kernel<<<waveBlocks, 256, 0, stream>>>(rowp, csr, bufB, el, er, filt, fo,
                                                        bufC, abuf, sbuf, n);
            agg2_kernel<<<waveBlocks, 256, 0, stream>>>(rowp, csr, bufC, abuf, sbuf,
                                                        bufA, n);
        }
        // out (+)= lin_w[c] * (Hc @ W2) (+ b2 on first channel)
        gemm_out<<<gemmBlocks, 256, 0, stream>>>(bufA, W2, b2, lin_w, out, n, c);
    }
}

// Round 3
// 1140.184 us; speedup vs baseline: 1.9888x; 1.7300x over previous
//
#include <hip/hip_runtime.h>
#include <hip/hip_bf16.h>
#include <math.h>

#define NEG_SLOPE 0.2f

// ---------------------------------------------------------------------------
// filt[l][c][r] = softmax_r(gt_w[l][c][:]) ; L*C = 4 rows, R = 3
// ---------------------------------------------------------------------------
__global__ void mkfilt(const float* __restrict__ gt_w, float* __restrict__ filt,
                       int rows /*L*C*/) {
    int i = threadIdx.x;
    if (i < rows) {
        const float* g = gt_w + i * 3;
        float m = fmaxf(g[0], fmaxf(g[1], g[2]));
        float e0 = __expf(g[0] - m), e1 = __expf(g[1] - m), e2 = __expf(g[2] - m);
        float s = e0 + e1 + e2;
        filt[i * 3 + 0] = e0 / s;
        filt[i * 3 + 1] = e1 / s;
        filt[i * 3 + 2] = e2 / s;
    }
}

// ---------------------------------------------------------------------------
// CSR build: histogram -> 3-phase parallel scan -> scatter (packed src|rel)
// ---------------------------------------------------------------------------
__global__ void hist_kernel(const int* __restrict__ dst, int* __restrict__ counts, int m) {
    int i = blockIdx.x * blockDim.x + threadIdx.x;
    if (i < m) atomicAdd(&counts[dst[i]], 1);
}

__global__ __launch_bounds__(256) void blocksum_kernel(const int* __restrict__ counts,
                                                       int* __restrict__ bsum, int n) {
    __shared__ int red[4];
    int i = blockIdx.x * 256 + threadIdx.x;
    int v = (i < n) ? counts[i] : 0;
    for (int off = 32; off; off >>= 1) v += __shfl_xor(v, off);
    if ((threadIdx.x & 63) == 0) red[threadIdx.x >> 6] = v;
    __syncthreads();
    if (threadIdx.x == 0) bsum[blockIdx.x] = red[0] + red[1] + red[2] + red[3];
}

__global__ __launch_bounds__(512) void scanb_kernel(int* __restrict__ bsum, int nb) {
    __shared__ int s[512];
    int t = threadIdx.x;
    int v = (t < nb) ? bsum[t] : 0;
    s[t] = v;
    __syncthreads();
    for (int off = 1; off < 512; off <<= 1) {
        int u = (t >= off) ? s[t - off] : 0;
        __syncthreads();
        s[t] += u;
        __syncthreads();
    }
    if (t < nb) bsum[t] = s[t] - v;   // exclusive
}

__global__ __launch_bounds__(256) void fill_kernel(const int* __restrict__ counts,
                                                   const int* __restrict__ bsum,
                                                   int* __restrict__ rowp,
                                                   int* __restrict__ cursor, int n, int m) {
    __shared__ int s[256];
    int t = threadIdx.x;
    int i = blockIdx.x * 256 + t;
    int v = (i < n) ? counts[i] : 0;
    s[t] = v;
    __syncthreads();
    for (int off = 1; off < 256; off <<= 1) {
        int u = (t >= off) ? s[t - off] : 0;
        __syncthreads();
        s[t] += u;
        __syncthreads();
    }
    if (i < n) {
        int ex = bsum[blockIdx.x] + s[t] - v;
        rowp[i] = ex;
        cursor[i] = ex;
    }
    if (i == 0) rowp[n] = m;
}

__global__ void scatter_kernel(const int* __restrict__ src, const int* __restrict__ dst,
                               const int* __restrict__ rel, int* __restrict__ cursor,
                               unsigned* __restrict__ csr, int m) {
    int i = blockIdx.x * blockDim.x + threadIdx.x;
    if (i < m) {
        int d = dst[i];
        int pos = atomicAdd(&cursor[d], 1);
        csr[pos] = (unsigned)src[i] | ((unsigned)rel[i] << 20);
    }
}

// ---------------------------------------------------------------------------
// GEMM: C[n,64] = A[n,64] @ W[64,64]; optional fused el/er epilogue
// ---------------------------------------------------------------------------
__global__ __launch_bounds__(256) void gemm64(const float* __restrict__ A,
                                              const float* __restrict__ W,
                                              float* __restrict__ C, int n,
                                              const float* __restrict__ attn_l,
                                              const float* __restrict__ attn_r,
                                              float* __restrict__ el,
                                              float* __restrict__ er) {
    __shared__ __align__(16) float sW[64 * 64];
    __shared__ __align__(16) float sA[64 * 68];
    __shared__ float sAl[64], sAr[64];
    int t = threadIdx.x;
    int row0 = blockIdx.x * 64;
    for (int i = t * 4; i < 64 * 64; i += 1024)
        *(float4*)&sW[i] = *(const float4*)&W[i];
    if (el && t < 64) { sAl[t] = attn_l[t]; sAr[t] = attn_r[t]; }
    int rows = n - row0; if (rows > 64) rows = 64;
    for (int i = t * 4; i < 64 * 64; i += 1024) {
        int r = i >> 6, cc = i & 63;
        float4 v = {0.f, 0.f, 0.f, 0.f};
        if (r < rows) v = *(const float4*)&A[(size_t)(row0 + r) * 64 + cc];
        *(float4*)&sA[r * 68 + cc] = v;
    }
    __syncthreads();
    int tr = (t >> 4) << 2;
    int tc = (t & 15) << 2;
    float acc[4][4] = {};
#pragma unroll
    for (int k = 0; k < 64; k += 4) {
        float4 a0 = *(const float4*)&sA[(tr + 0) * 68 + k];
        float4 a1 = *(const float4*)&sA[(tr + 1) * 68 + k];
        float4 a2 = *(const float4*)&sA[(tr + 2) * 68 + k];
        float4 a3 = *(const float4*)&sA[(tr + 3) * 68 + k];
#pragma unroll
        for (int kk = 0; kk < 4; ++kk) {
            float4 b = *(const float4*)&sW[(k + kk) * 64 + tc];
            float v0 = (&a0.x)[kk], v1 = (&a1.x)[kk], v2 = (&a2.x)[kk], v3 = (&a3.x)[kk];
            acc[0][0] += v0 * b.x; acc[0][1] += v0 * b.y; acc[0][2] += v0 * b.z; acc[0][3] += v0 * b.w;
            acc[1][0] += v1 * b.x; acc[1][1] += v1 * b.y; acc[1][2] += v1 * b.z; acc[1][3] += v1 * b.w;
            acc[2][0] += v2 * b.x; acc[2][1] += v2 * b.y; acc[2][2] += v2 * b.z; acc[2][3] += v2 * b.w;
            acc[3][0] += v3 * b.x; acc[3][1] += v3 * b.y; acc[3][2] += v3 * b.z; acc[3][3] += v3 * b.w;
        }
    }
    for (int i2 = 0; i2 < 4; ++i2) {
        int r = tr + i2;
        if (row0 + r < n) {
            float4 v = {acc[i2][0], acc[i2][1], acc[i2][2], acc[i2][3]};
            *(float4*)&C[(size_t)(row0 + r) * 64 + tc] = v;
        }
    }
    if (el) {
        float pl[4], pr[4];
#pragma unroll
        for (int i2 = 0; i2 < 4; ++i2) {
            float l = 0.f, r = 0.f;
#pragma unroll
            for (int j = 0; j < 4; ++j) {
                l += acc[i2][j] * sAl[tc + j];
                r += acc[i2][j] * sAr[tc + j];
            }
            pl[i2] = l; pr[i2] = r;
        }
#pragma unroll
        for (int off = 1; off < 16; off <<= 1) {
#pragma unroll
            for (int i2 = 0; i2 < 4; ++i2) {
                pl[i2] += __shfl_xor(pl[i2], off);
                pr[i2] += __shfl_xor(pr[i2], off);
            }
        }
        if ((t & 15) == 0) {
#pragma unroll
            for (int i2 = 0; i2 < 4; ++i2) {
                int r = row0 + tr + i2;
                if (r < n) { el[r] = pl[i2]; er[r] = pr[i2]; }
            }
        }
    }
}

// ---------------------------------------------------------------------------
// GAT pass 1 (NCH channels at once), one wave per dst node.
//  lane-par pass: degw_c = sum filt_c[rel]; e_c = exp(leaky(el_c[src]+er_c[v]))
//                 -> abuf_c[j]; ssum_c = sum e_c      (no max shift: exact)
//  serial pass (unroll 4): acc_c = sum filt_c[rel_j] * ft_c[src_j]
//  out_c[v] = acc_c / max(degw_c, >0 ? degw_c : 1);  sbuf_c[v] = 1/ssum_c
// ---------------------------------------------------------------------------
template <int NCH>
__global__ __launch_bounds__(256) void agg1_k(
        const int* __restrict__ rowp, const unsigned* __restrict__ csr,
        const float* __restrict__ filt, int fo0, int fo1,
        const float* __restrict__ ftA, const float* __restrict__ elA,
        const float* __restrict__ erA, float* __restrict__ oA,
        float* __restrict__ abA, float* __restrict__ sbA,
        const float* __restrict__ ftB, const float* __restrict__ elB,
        const float* __restrict__ erB, float* __restrict__ oB,
        float* __restrict__ abB, float* __restrict__ sbB, int n) {
    int w = (blockIdx.x * blockDim.x + threadIdx.x) >> 6;
    int lane = threadIdx.x & 63;
    if (w >= n) return;
    int base = rowp[w], end = rowp[w + 1];
    float fA0 = filt[fo0], fA1 = filt[fo0 + 1], fA2 = filt[fo0 + 2];
    float erAv = erA[w];
    float fB0 = 0.f, fB1 = 0.f, fB2 = 0.f, erBv = 0.f;
    if (NCH == 2) { fB0 = filt[fo1]; fB1 = filt[fo1 + 1]; fB2 = filt[fo1 + 2]; erBv = erB[w]; }

    // lane-parallel: degw, unnormalized attention, softmax denom
    float degA = 0.f, ssA = 0.f, degB = 0.f, ssB = 0.f;
    for (int j = base + lane; j < end; j += 64) {
        unsigned pk = csr[j];
        int s = pk & 0xFFFFF;
        int r = pk >> 20;
        degA += (r == 0) ? fA0 : ((r == 1) ? fA1 : fA2);
        float x = elA[s] + erAv;
        float e = __expf(x > 0.f ? x : NEG_SLOPE * x);
        abA[j] = e; ssA += e;
        if (NCH == 2) {
            degB += (r == 0) ? fB0 : ((r == 1) ? fB1 : fB2);
            float xb = elB[s] + erBv;
            float eb = __expf(xb > 0.f ? xb : NEG_SLOPE * xb);
            abB[j] = eb; ssB += eb;
        }
    }
    for (int off = 32; off; off >>= 1) {
        degA += __shfl_xor(degA, off); ssA += __shfl_xor(ssA, off);
        if (NCH == 2) { degB += __shfl_xor(degB, off); ssB += __shfl_xor(ssB, off); }
    }

    // serial gather, feature-parallel, unrolled x4 for MLP
    float accA = 0.f, accB = 0.f;
    int j = base;
    for (; j + 4 <= end; j += 4) {
        unsigned pk0 = csr[j], pk1 = csr[j + 1], pk2 = csr[j + 2], pk3 = csr[j + 3];
        int s0 = pk0 & 0xFFFFF, s1 = pk1 & 0xFFFFF, s2 = pk2 & 0xFFFFF, s3 = pk3 & 0xFFFFF;
        int r0 = pk0 >> 20, r1 = pk1 >> 20, r2 = pk2 >> 20, r3 = pk3 >> 20;
        float vA0 = ftA[(size_t)s0 * 64 + lane];
        float vA1 = ftA[(size_t)s1 * 64 + lane];
        float vA2 = ftA[(size_t)s2 * 64 + lane];
        float vA3 = ftA[(size_t)s3 * 64 + lane];
        float wA0 = (r0 == 0) ? fA0 : ((r0 == 1) ? fA1 : fA2);
        float wA1 = (r1 == 0) ? fA0 : ((r1 == 1) ? fA1 : fA2);
        float wA2 = (r2 == 0) ? fA0 : ((r2 == 1) ? fA1 : fA2);
        float wA3 = (r3 == 0) ? fA0 : ((r3 == 1) ? fA1 : fA2);
        accA += wA0 * vA0 + wA1 * vA1 + wA2 * vA2 + wA3 * vA3;
        if (NCH == 2) {
            float vB0 = ftB[(size_t)s0 * 64 + lane];
            float vB1 = ftB[(size_t)s1 * 64 + lane];
            float vB2 = ftB[(size_t)s2 * 64 + lane];
            float vB3 = ftB[(size_t)s3 * 64 + lane];
            float wB0 = (r0 == 0) ? fB0 : ((r0 == 1) ? fB1 : fB2);
            float wB1 = (r1 == 0) ? fB0 : ((r1 == 1) ? fB1 : fB2);
            float wB2 = (r2 == 0) ? fB0 : ((r2 == 1) ? fB1 : fB2);
            float wB3 = (r3 == 0) ? fB0 : ((r3 == 1) ? fB1 : fB2);
            accB += wB0 * vB0 + wB1 * vB1 + wB2 * vB2 + wB3 * vB3;
        }
    }
    for (; j < end; ++j) {
        unsigned pk = csr[j];
        int s = pk & 0xFFFFF;
        int r = pk >> 20;
        float wA = (r == 0) ? fA0 : ((r == 1) ? fA1 : fA2);
        accA += wA * ftA[(size_t)s * 64 + lane];
        if (NCH == 2) {
            float wB = (r == 0) ? fB0 : ((r == 1) ? fB1 : fB2);
            accB += wB * ftB[(size_t)s * 64 + lane];
        }
    }
    float dA = degA > 0.f ? degA : 1.f;
    oA[(size_t)w * 64 + lane] = accA / dA;
    if (lane == 0) sbA[w] = (ssA > 0.f) ? 1.f / ssA : 0.f;
    if (NCH == 2) {
        float dB = degB > 0.f ? degB : 1.f;
        oB[(size_t)w * 64 + lane] = accB / dB;
        if (lane == 0) sbB[w] = (ssB > 0.f) ? 1.f / ssB : 0.f;
    }
}

// ---------------------------------------------------------------------------
// GAT pass 2 (NCH channels): out_c[v] = (sum_j abuf_c[j] * ft_c[src_j]) * sbuf_c[v]
// ---------------------------------------------------------------------------
template <int NCH>
__global__ __launch_bounds__(256) void agg2_k(
        const int* __restrict__ rowp, const unsigned* __restrict__ csr,
        const float* __restrict__ ftA, const float* __restrict__ abA,
        const float* __restrict__ sbA, float* __restrict__ oA,
        const float* __restrict__ ftB, const float* __restrict__ abB,
        const float* __restrict__ sbB, float* __restrict__ oB, int n) {
    int w = (blockIdx.x * blockDim.x + threadIdx.x) >> 6;
    int lane = threadIdx.x & 63;
    if (w >= n) return;
    int base = rowp[w], end = rowp[w + 1];
    float invA = sbA[w];
    float invB = (NCH == 2) ? sbB[w] : 0.f;
    float accA = 0.f, accB = 0.f;
    int j = base;
    for (; j + 4 <= end; j += 4) {
        unsigned pk0 = csr[j], pk1 = csr[j + 1], pk2 = csr[j + 2], pk3 = csr[j + 3];
        int s0 = pk0 & 0xFFFFF, s1 = pk1 & 0xFFFFF, s2 = pk2 & 0xFFFFF, s3 = pk3 & 0xFFFFF;
        float a0 = abA[j], a1 = abA[j + 1], a2 = abA[j + 2], a3 = abA[j + 3];
        float vA0 = ftA[(size_t)s0 * 64 + lane];
        float vA1 = ftA[(size_t)s1 * 64 + lane];
        float vA2 = ftA[(size_t)s2 * 64 + lane];
        float vA3 = ftA[(size_t)s3 * 64 + lane];
        accA += a0 * vA0 + a1 * vA1 + a2 * vA2 + a3 * vA3;
        if (NCH == 2) {
            float b0 = abB[j], b1 = abB[j + 1], b2 = abB[j + 2], b3 = abB[j + 3];
            float vB0 = ftB[(size_t)s0 * 64 + lane];
            float vB1 = ftB[(size_t)s1 * 64 + lane];
            float vB2 = ftB[(size_t)s2 * 64 + lane];
            float vB3 = ftB[(size_t)s3 * 64 + lane];
            accB += b0 * vB0 + b1 * vB1 + b2 * vB2 + b3 * vB3;
        }
    }
    for (; j < end; ++j) {
        unsigned pk = csr[j];
        int s = pk & 0xFFFFF;
        accA += abA[j] * ftA[(size_t)s * 64 + lane];
        if (NCH == 2) accB += abB[j] * ftB[(size_t)s * 64 + lane];
    }
    oA[(size_t)w * 64 + lane] = accA * invA;
    if (NCH == 2) oB[(size_t)w * 64 + lane] = accB * invB;
}

// ---------------------------------------------------------------------------
// Final: out[n,50] (+)= lin_w[c] * (Hc @ W2) (+ b2 when c==0)
// ---------------------------------------------------------------------------
__global__ __launch_bounds__(256) void gemm_out(const float* __restrict__ A,
                                                const float* __restrict__ W2,
                                                const float* __restrict__ b2,
                                                const float* __restrict__ lin_w,
                                                float* __restrict__ out, int n, int c) {
    __shared__ __align__(16) float sW[64 * 50];
    __shared__ __align__(16) float sA[64 * 68];
    int t = threadIdx.x;
    int row0 = blockIdx.x * 64;
    for (int i = t; i < 64 * 50; i += 256) sW[i] = W2[i];
    int rows = n - row0; if (rows > 64) rows = 64;
    for (int i = t * 4; i < 64 * 64; i += 1024) {
        int r = i >> 6, cc = i & 63;
        float4 v = {0.f, 0.f, 0.f, 0.f};
        if (r < rows) v = *(const float4*)&A[(size_t)(row0 + r) * 64 + cc];
        *(float4*)&sA[r * 68 + cc] = v;
    }
    float lw = lin_w[c];
    __syncthreads();
    for (int i = t; i < 64 * 50; i += 256) {
        int r = i / 50, col = i - r * 50;
        if (row0 + r >= n) continue;
        float acc = 0.f;
#pragma unroll
        for (int k = 0; k < 64; ++k) acc += sA[r * 68 + k] * sW[k * 50 + col];
        size_t o = (size_t)(row0 + r) * 50 + col;
        float base = (c == 0) ? b2[col] : out[o];
        out[o] = base + lw * acc;
    }
}

// ---------------------------------------------------------------------------
extern "C" void kernel_launch(void* const* d_in, const int* in_sizes, int n_in,
                              void* d_out, int out_size, void* d_ws, size_t ws_size,
                              hipStream_t stream) {
    const float* h      = (const float*)d_in[0];
    const float* params = (const float*)d_in[1];
    const float* gt_w   = (const float*)d_in[2];
    const float* fc_w   = (const float*)d_in[3];
    const float* attn_l = (const float*)d_in[4];
    const float* attn_r = (const float*)d_in[5];
    const float* lin_w  = (const float*)d_in[6];
    const float* W2     = (const float*)d_in[7];
    const float* b2     = (const float*)d_in[8];
    const int*   src    = (const int*)d_in[9];
    const int*   dst    = (const int*)d_in[10];
    const int*   rel    = (const int*)d_in[11];

    const int n = in_sizes[0] / 64;      // 100000 nodes
    const int m = in_sizes[9];           // 1.8M edges
    const int C = 2, L = 2;
    float* out = (float*)d_out;

    char* base = (char*)d_ws;
    size_t off = 0;
    auto alloc = [&](size_t bytes) -> char* {
        char* p = base + off;
        off = (off + bytes + 255) & ~(size_t)255;
        return p;
    };
    const int nb = (n + 255) / 256;
    // common
    float*    filt   = (float*)alloc(L * C * 3 * sizeof(float));
    int*      counts = (int*)alloc((size_t)n * 4);
    int*      cursor = (int*)alloc((size_t)n * 4);
    int*      rowp   = (int*)alloc((size_t)(n + 1) * 4);
    int*      bsum   = (int*)alloc((size_t)nb * 4);
    unsigned* csr    = (unsigned*)alloc((size_t)m * 4);
    // channel A
    float*    elA  = (float*)alloc((size_t)n * 4);
    float*    erA  = (float*)alloc((size_t)n * 4);
    float*    sbA  = (float*)alloc((size_t)n * 4);
    float*    abA  = (float*)alloc((size_t)m * 4);
    float*    A0   = (float*)alloc((size_t)n * 64 * 4);
    float*    B0   = (float*)alloc((size_t)n * 64 * 4);
    float*    C0   = (float*)alloc((size_t)n * 64 * 4);
    // channel B (dual-path only)
    float*    elB  = (float*)alloc((size_t)n * 4);
    float*    erB  = (float*)alloc((size_t)n * 4);
    float*    sbB  = (float*)alloc((size_t)n * 4);
    float*    abB  = (float*)alloc((size_t)m * 4);
    float*    A1   = (float*)alloc((size_t)n * 64 * 4);
    float*    B1   = (float*)alloc((size_t)n * 64 * 4);
    float*    C1   = (float*)alloc((size_t)n * 64 * 4);
    bool dual = (off <= ws_size);

    // ---- CSR build ----
    hipMemsetAsync(counts, 0, (size_t)n * 4, stream);
    mkfilt<<<1, 64, 0, stream>>>(gt_w, filt, L * C);
    hist_kernel<<<(m + 255) / 256, 256, 0, stream>>>(dst, counts, m);
    blocksum_kernel<<<nb, 256, 0, stream>>>(counts, bsum, n);
    scanb_kernel<<<1, 512, 0, stream>>>(bsum, nb);
    fill_kernel<<<nb, 256, 0, stream>>>(counts, bsum, rowp, cursor, n, m);
    scatter_kernel<<<(m + 255) / 256, 256, 0, stream>>>(src, dst, rel, cursor, csr, m);

    const int gemmBlocks = (n + 63) / 64;
    const int waveBlocks = (n + 3) / 4;

    if (dual) {
        gemm64<<<gemmBlocks, 256, 0, stream>>>(h, params, A0, n,
                                               nullptr, nullptr, nullptr, nullptr);
        gemm64<<<gemmBlocks, 256, 0, stream>>>(h, params + 64 * 64, A1, n,
                                               nullptr, nullptr, nullptr, nullptr);
        for (int l = 0; l < L; ++l) {
            gemm64<<<gemmBlocks, 256, 0, stream>>>(A0, fc_w, B0, n, attn_l, attn_r, elA, erA);
            gemm64<<<gemmBlocks, 256, 0, stream>>>(A1, fc_w, B1, n, attn_l, attn_r, elB, erB);
            int fo0 = (l * C + 0) * 3, fo1 = (l * C + 1) * 3;
            agg1_k<2><<<waveBlocks, 256, 0, stream>>>(rowp, csr, filt, fo0, fo1,
                                                      B0, elA, erA, C0, abA, sbA,
                                                      B1, elB, erB, C1, abB, sbB, n);
            agg2_k<2><<<waveBlocks, 256, 0, stream>>>(rowp, csr,
                                                      C0, abA, sbA, A0,
                                                      C1, abB, sbB, A1, n);
        }
        gemm_out<<<gemmBlocks, 256, 0, stream>>>(A0, W2, b2, lin_w, out, n, 0);
        gemm_out<<<gemmBlocks, 256, 0, stream>>>(A1, W2, b2, lin_w, out, n, 1);
    } else {
        for (int c = 0; c < C; ++c) {
            gemm64<<<gemmBlocks, 256, 0, stream>>>(h, params + (size_t)c * 64 * 64, A0, n,
                                                   nullptr, nullptr, nullptr, nullptr);
            for (int l = 0; l < L; ++l) {
                gemm64<<<gemmBlocks, 256, 0, stream>>>(A0, fc_w, B0, n,
                                                       attn_l, attn_r, elA, erA);
                int fo = (l * C + c) * 3;
                agg1_k<1><<<waveBlocks, 256, 0, stream>>>(rowp, csr, filt, fo, fo,
                                                          B0, elA, erA, C0, abA, sbA,
                                                          nullptr, nullptr, nullptr,
                                                          nullptr, nullptr, nullptr, n);
                agg2_k<1><<<waveBlocks, 256, 0, stream>>>(rowp, csr,
                                                          C0, abA, sbA, A0,
                                                          nullptr, nullptr, nullptr,
                                                          nullptr, n);
            }
            gemm_out<<<gemmBlocks, 256, 0, stream>>>(A0, W2, b2, lin_w, out, n, c);
        }
    }
}

// Round 4
// 857.671 us; speedup vs baseline: 2.6439x; 1.3294x over previous
//
#include <hip/hip_runtime.h>
#include <hip/hip_bf16.h>
#include <math.h>

#define NEG_SLOPE 0.2f
#define NPB_SHIFT 7
#define NPB 128          // nodes per bucket

// ---------------------------------------------------------------------------
// filt[l][c][r] = softmax_r(gt_w[l][c][:]) ; L*C = 4 rows, R = 3
// ---------------------------------------------------------------------------
__global__ void mkfilt(const float* __restrict__ gt_w, float* __restrict__ filt,
                       int rows) {
    int i = threadIdx.x;
    if (i < rows) {
        const float* g = gt_w + i * 3;
        float m = fmaxf(g[0], fmaxf(g[1], g[2]));
        float e0 = __expf(g[0] - m), e1 = __expf(g[1] - m), e2 = __expf(g[2] - m);
        float s = e0 + e1 + e2;
        filt[i * 3 + 0] = e0 / s;
        filt[i * 3 + 1] = e1 / s;
        filt[i * 3 + 2] = e2 / s;
    }
}

// ---------------------------------------------------------------------------
// Wc[c] = params[c] @ fc_w  (64x64 @ 64x64), one block per channel
// ---------------------------------------------------------------------------
__global__ __launch_bounds__(256) void combw_kernel(const float* __restrict__ params,
                                                    const float* __restrict__ fc_w,
                                                    float* __restrict__ Wc) {
    __shared__ __align__(16) float sP[64 * 64], sF[64 * 64];
    const float* P = params + (size_t)blockIdx.x * 64 * 64;
    int t = threadIdx.x;
    for (int i = t * 4; i < 4096; i += 1024) {
        *(float4*)&sP[i] = *(const float4*)&P[i];
        *(float4*)&sF[i] = *(const float4*)&fc_w[i];
    }
    __syncthreads();
    float* O = Wc + (size_t)blockIdx.x * 64 * 64;
    for (int i = t; i < 4096; i += 256) {
        int r = i >> 6, c = i & 63;
        float acc = 0.f;
#pragma unroll
        for (int k = 0; k < 64; ++k) acc += sP[r * 64 + k] * sF[k * 64 + c];
        O[i] = acc;
    }
}

// ---------------------------------------------------------------------------
// Bucketed CSR build. bucket(v) = v >> NPB_SHIFT.
// ---------------------------------------------------------------------------
__global__ __launch_bounds__(256) void bcount_kernel(const int* __restrict__ dst,
                                                     int* __restrict__ bcnt, int m, int NB) {
    __shared__ int h[1024];
    for (int i = threadIdx.x; i < NB; i += 256) h[i] = 0;
    __syncthreads();
    int base = blockIdx.x * 4096;
#pragma unroll
    for (int k = 0; k < 16; ++k) {
        int i = base + k * 256 + threadIdx.x;
        if (i < m) atomicAdd(&h[dst[i] >> NPB_SHIFT], 1);
    }
    __syncthreads();
    for (int i = threadIdx.x; i < NB; i += 256)
        if (h[i]) atomicAdd(&bcnt[i], h[i]);
}

__global__ __launch_bounds__(1024) void bscan_kernel(const int* __restrict__ bcnt,
                                                     int* __restrict__ bbase,
                                                     int* __restrict__ bcur, int NB) {
    __shared__ int s[1024];
    int t = threadIdx.x;
    int v = (t < NB) ? bcnt[t] : 0;
    s[t] = v;
    __syncthreads();
    for (int off = 1; off < 1024; off <<= 1) {
        int u = (t >= off) ? s[t - off] : 0;
        __syncthreads();
        s[t] += u;
        __syncthreads();
    }
    if (t < NB) { bbase[t] = s[t] - v; bcur[t] = s[t] - v; }
    if (t == 1023) bbase[NB] = s[1023];
}

// pack: src(17) | rel(2)<<17 | dst_local(7)<<19
__global__ __launch_bounds__(256) void bscatter_kernel(const int* __restrict__ src,
                                                       const int* __restrict__ dst,
                                                       const int* __restrict__ rel,
                                                       int* __restrict__ bcur,
                                                       unsigned* __restrict__ ebuf,
                                                       int m, int NB) {
    __shared__ int h[1024];
    for (int i = threadIdx.x; i < NB; i += 256) h[i] = 0;
    __syncthreads();
    int base = blockIdx.x * 4096;
    unsigned pk[16];
    int bk[16];
#pragma unroll
    for (int k = 0; k < 16; ++k) {
        int i = base + k * 256 + threadIdx.x;
        bk[k] = -1;
        if (i < m) {
            int d = dst[i];
            bk[k] = d >> NPB_SHIFT;
            pk[k] = (unsigned)src[i] | ((unsigned)rel[i] << 17) |
                    ((unsigned)(d & (NPB - 1)) << 19);
            atomicAdd(&h[bk[k]], 1);
        }
    }
    __syncthreads();
    // reserve global range per bucket; h[b] becomes running cursor
    for (int b = threadIdx.x; b < NB; b += 256) {
        int c = h[b];
        if (c) h[b] = atomicAdd(&bcur[b], c);
    }
    __syncthreads();
#pragma unroll
    for (int k = 0; k < 16; ++k) {
        if (bk[k] >= 0) {
            int pos = atomicAdd(&h[bk[k]], 1);
            ebuf[pos] = pk[k];
        }
    }
}

// one block per bucket: per-node counts+scan in LDS -> rowp; scatter to csr
__global__ __launch_bounds__(256) void bfinal_kernel(const unsigned* __restrict__ ebuf,
                                                     const int* __restrict__ bbase,
                                                     int* __restrict__ rowp,
                                                     unsigned* __restrict__ csr,
                                                     int n, int m, int NB) {
    __shared__ int cnt[NPB], cur[NPB], sc[NPB];
    int b = blockIdx.x;
    int t = threadIdx.x;
    int e0 = bbase[b], e1 = bbase[b + 1];
    if (t < NPB) cnt[t] = 0;
    __syncthreads();
    for (int j = e0 + t; j < e1; j += 256)
        atomicAdd(&cnt[(ebuf[j] >> 19) & (NPB - 1)], 1);
    __syncthreads();
    int v0 = (t < NPB) ? cnt[t] : 0;
    if (t < NPB) sc[t] = v0;
    __syncthreads();
    for (int off = 1; off < NPB; off <<= 1) {
        int u = (t >= off && t < NPB) ? sc[t - off] : 0;
        __syncthreads();
        if (t < NPB) sc[t] += u;
        __syncthreads();
    }
    if (t < NPB) {
        int ex = e0 + sc[t] - v0;          // exclusive prefix + bucket base
        cur[t] = ex;
        int v = b * NPB + t;
        if (v < n) rowp[v] = ex;
    }
    if (b == 0 && t == 0) rowp[n] = m;
    __syncthreads();
    for (int j = e0 + t; j < e1; j += 256) {
        unsigned pk = ebuf[j];
        int dl = (pk >> 19) & (NPB - 1);
        int pos = atomicAdd(&cur[dl], 1);
        csr[pos] = (pk & 0x1FFFF) | (((pk >> 17) & 3) << 20);
    }
}

// ---------------------------------------------------------------------------
// GEMM: C[n,64] = A[n,64] @ W[64,64]; optional fused el/er epilogue
// ---------------------------------------------------------------------------
__global__ __launch_bounds__(256) void gemm64(const float* __restrict__ A,
                                              const float* __restrict__ W,
                                              float* __restrict__ C, int n,
                                              const float* __restrict__ attn_l,
                                              const float* __restrict__ attn_r,
                                              float* __restrict__ el,
                                              float* __restrict__ er) {
    __shared__ __align__(16) float sW[64 * 64];
    __shared__ __align__(16) float sA[64 * 68];
    __shared__ float sAl[64], sAr[64];
    int t = threadIdx.x;
    int row0 = blockIdx.x * 64;
    for (int i = t * 4; i < 64 * 64; i += 1024)
        *(float4*)&sW[i] = *(const float4*)&W[i];
    if (el && t < 64) { sAl[t] = attn_l[t]; sAr[t] = attn_r[t]; }
    int rows = n - row0; if (rows > 64) rows = 64;
    for (int i = t * 4; i < 64 * 64; i += 1024) {
        int r = i >> 6, cc = i & 63;
        float4 v = {0.f, 0.f, 0.f, 0.f};
        if (r < rows) v = *(const float4*)&A[(size_t)(row0 + r) * 64 + cc];
        *(float4*)&sA[r * 68 + cc] = v;
    }
    __syncthreads();
    int tr = (t >> 4) << 2;
    int tc = (t & 15) << 2;
    float acc[4][4] = {};
#pragma unroll
    for (int k = 0; k < 64; k += 4) {
        float4 a0 = *(const float4*)&sA[(tr + 0) * 68 + k];
        float4 a1 = *(const float4*)&sA[(tr + 1) * 68 + k];
        float4 a2 = *(const float4*)&sA[(tr + 2) * 68 + k];
        float4 a3 = *(const float4*)&sA[(tr + 3) * 68 + k];
#pragma unroll
        for (int kk = 0; kk < 4; ++kk) {
            float4 b = *(const float4*)&sW[(k + kk) * 64 + tc];
            float v0 = (&a0.x)[kk], v1 = (&a1.x)[kk], v2 = (&a2.x)[kk], v3 = (&a3.x)[kk];
            acc[0][0] += v0 * b.x; acc[0][1] += v0 * b.y; acc[0][2] += v0 * b.z; acc[0][3] += v0 * b.w;
            acc[1][0] += v1 * b.x; acc[1][1] += v1 * b.y; acc[1][2] += v1 * b.z; acc[1][3] += v1 * b.w;
            acc[2][0] += v2 * b.x; acc[2][1] += v2 * b.y; acc[2][2] += v2 * b.z; acc[2][3] += v2 * b.w;
            acc[3][0] += v3 * b.x; acc[3][1] += v3 * b.y; acc[3][2] += v3 * b.z; acc[3][3] += v3 * b.w;
        }
    }
    for (int i2 = 0; i2 < 4; ++i2) {
        int r = tr + i2;
        if (row0 + r < n) {
            float4 v = {acc[i2][0], acc[i2][1], acc[i2][2], acc[i2][3]};
            *(float4*)&C[(size_t)(row0 + r) * 64 + tc] = v;
        }
    }
    if (el) {
        float pl[4], pr[4];
#pragma unroll
        for (int i2 = 0; i2 < 4; ++i2) {
            float l = 0.f, r = 0.f;
#pragma unroll
            for (int j = 0; j < 4; ++j) {
                l += acc[i2][j] * sAl[tc + j];
                r += acc[i2][j] * sAr[tc + j];
            }
            pl[i2] = l; pr[i2] = r;
        }
#pragma unroll
        for (int off = 1; off < 16; off <<= 1) {
#pragma unroll
            for (int i2 = 0; i2 < 4; ++i2) {
                pl[i2] += __shfl_xor(pl[i2], off);
                pr[i2] += __shfl_xor(pr[i2], off);
            }
        }
        if ((t & 15) == 0) {
#pragma unroll
            for (int i2 = 0; i2 < 4; ++i2) {
                int r = row0 + tr + i2;
                if (r < n) { el[r] = pl[i2]; er[r] = pr[i2]; }
            }
        }
    }
}

// ---------------------------------------------------------------------------
// GAT pass 1 (NCH channels at once), one wave per dst node.
// ---------------------------------------------------------------------------
template <int NCH>
__global__ __launch_bounds__(256) void agg1_k(
        const int* __restrict__ rowp, const unsigned* __restrict__ csr,
        const float* __restrict__ filt, int fo0, int fo1,
        const float* __restrict__ ftA, const float* __restrict__ elA,
        const float* __restrict__ erA, float* __restrict__ oA,
        float* __restrict__ abA, float* __restrict__ sbA,
        const float* __restrict__ ftB, const float* __restrict__ elB,
        const float* __restrict__ erB, float* __restrict__ oB,
        float* __restrict__ abB, float* __restrict__ sbB, int n) {
    int w = (blockIdx.x * blockDim.x + threadIdx.x) >> 6;
    int lane = threadIdx.x & 63;
    if (w >= n) return;
    int base = rowp[w], end = rowp[w + 1];
    float fA0 = filt[fo0], fA1 = filt[fo0 + 1], fA2 = filt[fo0 + 2];
    float erAv = erA[w];
    float fB0 = 0.f, fB1 = 0.f, fB2 = 0.f, erBv = 0.f;
    if (NCH == 2) { fB0 = filt[fo1]; fB1 = filt[fo1 + 1]; fB2 = filt[fo1 + 2]; erBv = erB[w]; }

    float degA = 0.f, ssA = 0.f, degB = 0.f, ssB = 0.f;
    for (int j = base + lane; j < end; j += 64) {
        unsigned pk = csr[j];
        int s = pk & 0xFFFFF;
        int r = pk >> 20;
        degA += (r == 0) ? fA0 : ((r == 1) ? fA1 : fA2);
        float x = elA[s] + erAv;
        float e = __expf(x > 0.f ? x : NEG_SLOPE * x);
        abA[j] = e; ssA += e;
        if (NCH == 2) {
            degB += (r == 0) ? fB0 : ((r == 1) ? fB1 : fB2);
            float xb = elB[s] + erBv;
            float eb = __expf(xb > 0.f ? xb : NEG_SLOPE * xb);
            abB[j] = eb; ssB += eb;
        }
    }
    for (int off = 32; off; off >>= 1) {
        degA += __shfl_xor(degA, off); ssA += __shfl_xor(ssA, off);
        if (NCH == 2) { degB += __shfl_xor(degB, off); ssB += __shfl_xor(ssB, off); }
    }

    float accA = 0.f, accB = 0.f;
    int j = base;
    for (; j + 4 <= end; j += 4) {
        unsigned pk0 = csr[j], pk1 = csr[j + 1], pk2 = csr[j + 2], pk3 = csr[j + 3];
        int s0 = pk0 & 0xFFFFF, s1 = pk1 & 0xFFFFF, s2 = pk2 & 0xFFFFF, s3 = pk3 & 0xFFFFF;
        int r0 = pk0 >> 20, r1 = pk1 >> 20, r2 = pk2 >> 20, r3 = pk3 >> 20;
        float vA0 = ftA[(size_t)s0 * 64 + lane];
        float vA1 = ftA[(size_t)s1 * 64 + lane];
        float vA2 = ftA[(size_t)s2 * 64 + lane];
        float vA3 = ftA[(size_t)s3 * 64 + lane];
        float wA0 = (r0 == 0) ? fA0 : ((r0 == 1) ? fA1 : fA2);
        float wA1 = (r1 == 0) ? fA0 : ((r1 == 1) ? fA1 : fA2);
        float wA2 = (r2 == 0) ? fA0 : ((r2 == 1) ? fA1 : fA2);
        float wA3 = (r3 == 0) ? fA0 : ((r3 == 1) ? fA1 : fA2);
        accA += wA0 * vA0 + wA1 * vA1 + wA2 * vA2 + wA3 * vA3;
        if (NCH == 2) {
            float vB0 = ftB[(size_t)s0 * 64 + lane];
            float vB1 = ftB[(size_t)s1 * 64 + lane];
            float vB2 = ftB[(size_t)s2 * 64 + lane];
            float vB3 = ftB[(size_t)s3 * 64 + lane];
            float wB0 = (r0 == 0) ? fB0 : ((r0 == 1) ? fB1 : fB2);
            float wB1 = (r1 == 0) ? fB0 : ((r1 == 1) ? fB1 : fB2);
            float wB2 = (r2 == 0) ? fB0 : ((r2 == 1) ? fB1 : fB2);
            float wB3 = (r3 == 0) ? fB0 : ((r3 == 1) ? fB1 : fB2);
            accB += wB0 * vB0 + wB1 * vB1 + wB2 * vB2 + wB3 * vB3;
        }
    }
    for (; j < end; ++j) {
        unsigned pk = csr[j];
        int s = pk & 0xFFFFF;
        int r = pk >> 20;
        float wA = (r == 0) ? fA0 : ((r == 1) ? fA1 : fA2);
        accA += wA * ftA[(size_t)s * 64 + lane];
        if (NCH == 2) {
            float wB = (r == 0) ? fB0 : ((r == 1) ? fB1 : fB2);
            accB += wB * ftB[(size_t)s * 64 + lane];
        }
    }
    float dA = degA > 0.f ? degA : 1.f;
    oA[(size_t)w * 64 + lane] = accA / dA;
    if (lane == 0) sbA[w] = (ssA > 0.f) ? 1.f / ssA : 0.f;
    if (NCH == 2) {
        float dB = degB > 0.f ? degB : 1.f;
        oB[(size_t)w * 64 + lane] = accB / dB;
        if (lane == 0) sbB[w] = (ssB > 0.f) ? 1.f / ssB : 0.f;
    }
}

// ---------------------------------------------------------------------------
// GAT pass 2 (NCH channels)
// ---------------------------------------------------------------------------
template <int NCH>
__global__ __launch_bounds__(256) void agg2_k(
        const int* __restrict__ rowp, const unsigned* __restrict__ csr,
        const float* __restrict__ ftA, const float* __restrict__ abA,
        const float* __restrict__ sbA, float* __restrict__ oA,
        const float* __restrict__ ftB, const float* __restrict__ abB,
        const float* __restrict__ sbB, float* __restrict__ oB, int n) {
    int w = (blockIdx.x * blockDim.x + threadIdx.x) >> 6;
    int lane = threadIdx.x & 63;
    if (w >= n) return;
    int base = rowp[w], end = rowp[w + 1];
    float invA = sbA[w];
    float invB = (NCH == 2) ? sbB[w] : 0.f;
    float accA = 0.f, accB = 0.f;
    int j = base;
    for (; j + 4 <= end; j += 4) {
        unsigned pk0 = csr[j], pk1 = csr[j + 1], pk2 = csr[j + 2], pk3 = csr[j + 3];
        int s0 = pk0 & 0xFFFFF, s1 = pk1 & 0xFFFFF, s2 = pk2 & 0xFFFFF, s3 = pk3 & 0xFFFFF;
        float a0 = abA[j], a1 = abA[j + 1], a2 = abA[j + 2], a3 = abA[j + 3];
        float vA0 = ftA[(size_t)s0 * 64 + lane];
        float vA1 = ftA[(size_t)s1 * 64 + lane];
        float vA2 = ftA[(size_t)s2 * 64 + lane];
        float vA3 = ftA[(size_t)s3 * 64 + lane];
        accA += a0 * vA0 + a1 * vA1 + a2 * vA2 + a3 * vA3;
        if (NCH == 2) {
            float b0 = abB[j], b1 = abB[j + 1], b2 = abB[j + 2], b3 = abB[j + 3];
            float vB0 = ftB[(size_t)s0 * 64 + lane];
            float vB1 = ftB[(size_t)s1 * 64 + lane];
            float vB2 = ftB[(size_t)s2 * 64 + lane];
            float vB3 = ftB[(size_t)s3 * 64 + lane];
            accB += b0 * vB0 + b1 * vB1 + b2 * vB2 + b3 * vB3;
        }
    }
    for (; j < end; ++j) {
        unsigned pk = csr[j];
        int s = pk & 0xFFFFF;
        accA += abA[j] * ftA[(size_t)s * 64 + lane];
        if (NCH == 2) accB += abB[j] * ftB[(size_t)s * 64 + lane];
    }
    oA[(size_t)w * 64 + lane] = accA * invA;
    if (NCH == 2) oB[(size_t)w * 64 + lane] = accB * invB;
}

// ---------------------------------------------------------------------------
// Fused final: out = b2 + (lw0*A0 + lw1*A1) @ W2
// ---------------------------------------------------------------------------
__global__ __launch_bounds__(256) void gemm_out2(const float* __restrict__ A0,
                                                 const float* __restrict__ A1,
                                                 const float* __restrict__ W2,
                                                 const float* __restrict__ b2,
                                                 const float* __restrict__ lin_w,
                                                 float* __restrict__ out, int n) {
    __shared__ __align__(16) float sW[64 * 50];
    __shared__ __align__(16) float sA[64 * 68];
    int t = threadIdx.x;
    int row0 = blockIdx.x * 64;
    float lw0 = lin_w[0], lw1 = lin_w[1];
    for (int i = t; i < 64 * 50; i += 256) sW[i] = W2[i];
    int rows = n - row0; if (rows > 64) rows = 64;
    for (int i = t * 4; i < 4096; i += 1024) {
        int r = i >> 6, cc = i & 63;
        float4 v = {0.f, 0.f, 0.f, 0.f};
        if (r < rows) {
            float4 a = *(const float4*)&A0[(size_t)(row0 + r) * 64 + cc];
            float4 b = *(const float4*)&A1[(size_t)(row0 + r) * 64 + cc];
            v.x = lw0 * a.x + lw1 * b.x; v.y = lw0 * a.y + lw1 * b.y;
            v.z = lw0 * a.z + lw1 * b.z; v.w = lw0 * a.w + lw1 * b.w;
        }
        *(float4*)&sA[r * 68 + cc] = v;
    }
    __syncthreads();
    for (int i = t; i < 64 * 50; i += 256) {
        int r = i / 50, col = i - r * 50;
        if (row0 + r >= n) continue;
        float acc = 0.f;
#pragma unroll
        for (int k = 0; k < 64; ++k) acc += sA[r * 68 + k] * sW[k * 50 + col];
        out[(size_t)(row0 + r) * 50 + col] = b2[col] + acc;
    }
}

// per-channel fallback version
__global__ __launch_bounds__(256) void gemm_out(const float* __restrict__ A,
                                                const float* __restrict__ W2,
                                                const float* __restrict__ b2,
                                                const float* __restrict__ lin_w,
                                                float* __restrict__ out, int n, int c) {
    __shared__ __align__(16) float sW[64 * 50];
    __shared__ __align__(16) float sA[64 * 68];
    int t = threadIdx.x;
    int row0 = blockIdx.x * 64;
    for (int i = t; i < 64 * 50; i += 256) sW[i] = W2[i];
    int rows = n - row0; if (rows > 64) rows = 64;
    for (int i = t * 4; i < 4096; i += 1024) {
        int r = i >> 6, cc = i & 63;
        float4 v = {0.f, 0.f, 0.f, 0.f};
        if (r < rows) v = *(const float4*)&A[(size_t)(row0 + r) * 64 + cc];
        *(float4*)&sA[r * 68 + cc] = v;
    }
    float lw = lin_w[c];
    __syncthreads();
    for (int i = t; i < 64 * 50; i += 256) {
        int r = i / 50, col = i - r * 50;
        if (row0 + r >= n) continue;
        float acc = 0.f;
#pragma unroll
        for (int k = 0; k < 64; ++k) acc += sA[r * 68 + k] * sW[k * 50 + col];
        size_t o = (size_t)(row0 + r) * 50 + col;
        float base = (c == 0) ? b2[col] : out[o];
        out[o] = base + lw * acc;
    }
}

// ---------------------------------------------------------------------------
extern "C" void kernel_launch(void* const* d_in, const int* in_sizes, int n_in,
                              void* d_out, int out_size, void* d_ws, size_t ws_size,
                              hipStream_t stream) {
    const float* h      = (const float*)d_in[0];
    const float* params = (const float*)d_in[1];
    const float* gt_w   = (const float*)d_in[2];
    const float* fc_w   = (const float*)d_in[3];
    const float* attn_l = (const float*)d_in[4];
    const float* attn_r = (const float*)d_in[5];
    const float* lin_w  = (const float*)d_in[6];
    const float* W2     = (const float*)d_in[7];
    const float* b2     = (const float*)d_in[8];
    const int*   src    = (const int*)d_in[9];
    const int*   dst    = (const int*)d_in[10];
    const int*   rel    = (const int*)d_in[11];

    const int n = in_sizes[0] / 64;      // 100000 nodes
    const int m = in_sizes[9];           // 1.8M edges
    const int C = 2, L = 2;
    float* out = (float*)d_out;

    char* base = (char*)d_ws;
    size_t off = 0;
    auto alloc = [&](size_t bytes) -> char* {
        char* p = base + off;
        off = (off + bytes + 255) & ~(size_t)255;
        return p;
    };
    const int NB = (n + NPB - 1) >> NPB_SHIFT;       // 782 buckets
    const int nchunks = (m + 4095) / 4096;
    // common
    float*    filt  = (float*)alloc(L * C * 3 * sizeof(float));
    float*    Wc    = (float*)alloc((size_t)C * 64 * 64 * 4);
    int*      bcnt  = (int*)alloc((size_t)NB * 4);
    int*      bbase = (int*)alloc((size_t)(NB + 1) * 4);
    int*      bcur  = (int*)alloc((size_t)NB * 4);
    int*      rowp  = (int*)alloc((size_t)(n + 1) * 4);
    unsigned* ebuf  = (unsigned*)alloc((size_t)m * 4);
    unsigned* csr   = (unsigned*)alloc((size_t)m * 4);
    // channel A
    float*    elA  = (float*)alloc((size_t)n * 4);
    float*    erA  = (float*)alloc((size_t)n * 4);
    float*    sbA  = (float*)alloc((size_t)n * 4);
    float*    abA  = (float*)alloc((size_t)m * 4);
    float*    A0   = (float*)alloc((size_t)n * 64 * 4);
    float*    B0   = (float*)alloc((size_t)n * 64 * 4);
    float*    C0   = (float*)alloc((size_t)n * 64 * 4);
    // channel B
    float*    elB  = (float*)alloc((size_t)n * 4);
    float*    erB  = (float*)alloc((size_t)n * 4);
    float*    sbB  = (float*)alloc((size_t)n * 4);
    float*    abB  = (float*)alloc((size_t)m * 4);
    float*    A1   = (float*)alloc((size_t)n * 64 * 4);
    float*    B1   = (float*)alloc((size_t)n * 64 * 4);
    float*    C1   = (float*)alloc((size_t)n * 64 * 4);
    bool dual = (off <= ws_size);

    // ---- CSR build: bucket counting sort ----
    hipMemsetAsync(bcnt, 0, (size_t)NB * 4, stream);
    mkfilt<<<1, 64, 0, stream>>>(gt_w, filt, L * C);
    combw_kernel<<<C, 256, 0, stream>>>(params, fc_w, Wc);
    bcount_kernel<<<nchunks, 256, 0, stream>>>(dst, bcnt, m, NB);
    bscan_kernel<<<1, 1024, 0, stream>>>(bcnt, bbase, bcur, NB);
    bscatter_kernel<<<nchunks, 256, 0, stream>>>(src, dst, rel, bcur, ebuf, m, NB);
    bfinal_kernel<<<NB, 256, 0, stream>>>(ebuf, bbase, rowp, csr, n, m, NB);

    const int gemmBlocks = (n + 63) / 64;
    const int waveBlocks = (n + 3) / 4;

    if (dual) {
        for (int l = 0; l < L; ++l) {
            if (l == 0) {
                // ft0 = h @ (params[c] @ fc_w)  — skips materializing h@params
                gemm64<<<gemmBlocks, 256, 0, stream>>>(h, Wc, B0, n,
                                                       attn_l, attn_r, elA, erA);
                gemm64<<<gemmBlocks, 256, 0, stream>>>(h, Wc + 64 * 64, B1, n,
                                                       attn_l, attn_r, elB, erB);
            } else {
                gemm64<<<gemmBlocks, 256, 0, stream>>>(A0, fc_w, B0, n,
                                                       attn_l, attn_r, elA, erA);
                gemm64<<<gemmBlocks, 256, 0, stream>>>(A1, fc_w, B1, n,
                                                       attn_l, attn_r, elB, erB);
            }
            int fo0 = (l * C + 0) * 3, fo1 = (l * C + 1) * 3;
            agg1_k<2><<<waveBlocks, 256, 0, stream>>>(rowp, csr, filt, fo0, fo1,
                                                      B0, elA, erA, C0, abA, sbA,
                                                      B1, elB, erB, C1, abB, sbB, n);
            agg2_k<2><<<waveBlocks, 256, 0, stream>>>(rowp, csr,
                                                      C0, abA, sbA, A0,
                                                      C1, abB, sbB, A1, n);
        }
        gemm_out2<<<gemmBlocks, 256, 0, stream>>>(A0, A1, W2, b2, lin_w, out, n);
    } else {
        for (int c = 0; c < C; ++c) {
            for (int l = 0; l < L; ++l) {
                const float* Ain = (l == 0) ? h : A0;
                const float* Win = (l == 0) ? (Wc + (size_t)c * 64 * 64) : fc_w;
                gemm64<<<gemmBlocks, 256, 0, stream>>>(Ain, Win, B0, n,
                                                       attn_l, attn_r, elA, erA);
                int fo = (l * C + c) * 3;
                agg1_k<1><<<waveBlocks, 256, 0, stream>>>(rowp, csr, filt, fo, fo,
                                                          B0, elA, erA, C0, abA, sbA,
                                                          nullptr, nullptr, nullptr,
                                                          nullptr, nullptr, nullptr, n);
                agg2_k<1><<<waveBlocks, 256, 0, stream>>>(rowp, csr,
                                                          C0, abA, sbA, A0,
                                                          nullptr, nullptr, nullptr,
                                                          nullptr, n);
            }
            gemm_out<<<gemmBlocks, 256, 0, stream>>>(A0, W2, b2, lin_w, out, n, c);
        }
    }
}